// Round 21
// baseline (281.135 us; speedup 1.0000x reference)
//
#include <hip/hip_runtime.h>

#define N_NODES 100000
#define N_EDGES 3200000
#define EMB 128
#define N_GRAPH 1024
#define N_CLASS 10
#define CAP 96  // padded CSR capacity; P(deg>=96)~4e-20 per node (mean deg 32)

#define EPB 5120                         // edges per hist/scatter block
#define NBLK_E (N_EDGES / EPB)           // 625
#define NBK 391                          // ceil(100000/256) buckets of 256 nodes
#define NTOT (NBK * NBLK_E)              // 244375
#define SCAN_B 1024
#define NB_SCAN ((NTOT + SCAN_B - 1) / SCAN_B)  // 239

#define EMBED_BLKS (N_NODES * 16 / 256)  // 6250
#define WCAT_BLKS 256                    // 2 x 128

typedef unsigned int uint32;
typedef __attribute__((ext_vector_type(8))) short bf16x8;
typedef __attribute__((ext_vector_type(4))) float f32x4;
typedef __attribute__((ext_vector_type(2))) float f32x2;

__device__ inline unsigned short f2bf(float f) {
  unsigned u = __float_as_uint(f);
  u += 0x7fffu + ((u >> 16) & 1u);
  return (unsigned short)(u >> 16);
}
__device__ inline float bf2f(unsigned short s) {
  return __uint_as_float(((unsigned)s) << 16);
}
__device__ inline unsigned char f2fp8(float v) {
  return (unsigned char)(__builtin_amdgcn_cvt_pk_fp8_f32(v, v, 0, false) & 0xff);
}

// ---- A: fused bucket-histogram (LDS atomics only) + embedding + wcat --------
__global__ __launch_bounds__(256) void k_hist(
    const int* __restrict__ dst, int* __restrict__ counts,
    const int* __restrict__ nf, const float* __restrict__ se,
    const float* __restrict__ ce, const float* __restrict__ pe,
    unsigned short* __restrict__ X, unsigned char* __restrict__ X8,
    const float* __restrict__ w1l, const float* __restrict__ w1r,
    const float* __restrict__ w2l, const float* __restrict__ w2r,
    unsigned short* __restrict__ wc1, unsigned short* __restrict__ wc2) {
  int b = blockIdx.x;
  int tid = threadIdx.x;
  if (b < NBLK_E) {
    __shared__ int h[NBK];
    for (int i = tid; i < NBK; i += 256) h[i] = 0;
    __syncthreads();
    int base = b * EPB;
#pragma unroll
    for (int it = 0; it < 20; ++it) {
      int d = dst[base + it * 256 + tid];
      atomicAdd(&h[d >> 8], 1);
    }
    __syncthreads();
    for (int i = tid; i < NBK; i += 256) counts[i * NBLK_E + b] = h[i];
  } else if (b < NBLK_E + EMBED_BLKS) {
    int gid = (b - NBLK_E) * 256 + tid;  // N_NODES*16 threads
    int node = gid >> 4;
    int q = (gid & 15) * 8;
    int s = nf[node * 3 + 0];
    int c = nf[node * 3 + 1];
    int p = nf[node * 3 + 2];
    const float* ps = se + s * EMB + q;
    const float* pc = ce + c * EMB + q;
    const float* pp = pe + p * EMB + q;
    float4 a0 = *(const float4*)ps, a1 = *(const float4*)(ps + 4);
    float4 b0 = *(const float4*)pc, b1 = *(const float4*)(pc + 4);
    float4 d0 = *(const float4*)pp, d1 = *(const float4*)(pp + 4);
    float r0 = a0.x + b0.x + d0.x, r1 = a0.y + b0.y + d0.y;
    float r2 = a0.z + b0.z + d0.z, r3 = a0.w + b0.w + d0.w;
    float r4 = a1.x + b1.x + d1.x, r5 = a1.y + b1.y + d1.y;
    float r6 = a1.z + b1.z + d1.z, r7 = a1.w + b1.w + d1.w;
    uint4 o;
    o.x = (uint32)f2bf(r0) | ((uint32)f2bf(r1) << 16);
    o.y = (uint32)f2bf(r2) | ((uint32)f2bf(r3) << 16);
    o.z = (uint32)f2bf(r4) | ((uint32)f2bf(r5) << 16);
    o.w = (uint32)f2bf(r6) | ((uint32)f2bf(r7) << 16);
    *(uint4*)(X + (size_t)node * EMB + q) = o;
    int w0 = __builtin_amdgcn_cvt_pk_fp8_f32(r0, r1, 0, false);
    w0 = __builtin_amdgcn_cvt_pk_fp8_f32(r2, r3, w0, true);
    int w1 = __builtin_amdgcn_cvt_pk_fp8_f32(r4, r5, 0, false);
    w1 = __builtin_amdgcn_cvt_pk_fp8_f32(r6, r7, w1, true);
    uint2 o8;
    o8.x = (uint32)w0;
    o8.y = (uint32)w1;
    *(uint2*)(X8 + (size_t)node * EMB + q) = o8;
  } else {
    int wb = b - (NBLK_E + EMBED_BLKS);  // 0..255
    const float* wl = (wb < 128) ? w1l : w2l;
    const float* wr = (wb < 128) ? w1r : w2r;
    unsigned short* wcat = (wb < 128) ? wc1 : wc2;
    int gid = (wb & 127) * 256 + tid;  // 32768 elems
    int j = gid >> 8;
    int k = gid & 255;
    float v = (k < EMB) ? wl[j * EMB + k] : wr[j * EMB + (k - EMB)];
    wcat[gid] = f2bf(v);
  }
}

// ---------------- scan over flattened counts [bucket][block] -----------------
__global__ void k_scan1(int* __restrict__ data, int* __restrict__ part) {
  __shared__ int t[SCAN_B];
  int tid = threadIdx.x;
  int gid = blockIdx.x * SCAN_B + tid;
  int v = (gid < NTOT) ? data[gid] : 0;
  t[tid] = v;
  __syncthreads();
  for (int s = 1; s < SCAN_B; s <<= 1) {
    int u = (tid >= s) ? t[tid - s] : 0;
    __syncthreads();
    t[tid] += u;
    __syncthreads();
  }
  if (gid < NTOT) data[gid] = t[tid] - v;  // exclusive, block-local
  if (tid == SCAN_B - 1) part[blockIdx.x] = t[tid];
}

__global__ void k_scan2(int* __restrict__ part) {
  __shared__ int t[512];
  int tid = threadIdx.x;  // 512
  int v = (tid < NB_SCAN) ? part[tid] : 0;
  t[tid] = v;
  __syncthreads();
  for (int s = 1; s < 512; s <<= 1) {
    int u = (tid >= s) ? t[tid - s] : 0;
    __syncthreads();
    t[tid] += u;
    __syncthreads();
  }
  if (tid < NB_SCAN) part[tid] = t[tid] - v;
}

// ---- C: partition packed (dlocal,src); scanned column preloaded in LDS ------
// 1024 threads/block for occupancy (5 edges/thread)
__global__ __launch_bounds__(1024) void k_part(const int* __restrict__ src,
                                               const int* __restrict__ dst,
                                               const int* __restrict__ counts,
                                               const int* __restrict__ part,
                                               uint32* __restrict__ psort) {
  __shared__ int h[NBK];
  __shared__ int scol[NBK];
  int b = blockIdx.x;
  int tid = threadIdx.x;
  for (int i = tid; i < NBK; i += 1024) {
    h[i] = 0;
    int idx = i * NBLK_E + b;
    scol[i] = counts[idx] + part[idx >> 10];
  }
  __syncthreads();
  int base = b * EPB;
#pragma unroll
  for (int it = 0; it < 5; ++it) {
    int e = base + it * 1024 + tid;
    int d = dst[e];
    int s = src[e];
    int r = atomicAdd(&h[d >> 8], 1);
    psort[scol[d >> 8] + r] = ((uint32)(d & 255) << 24) | (uint32)s;
  }
}

// ---- D: per-bucket CSR build (LDS ranks, L2-local scatter) + degi -----------
__global__ __launch_bounds__(256) void k_csr(const uint32* __restrict__ psort,
                                             const int* __restrict__ counts,
                                             const int* __restrict__ part,
                                             int* __restrict__ csrp,
                                             int* __restrict__ degi) {
  __shared__ int h[256];
  int b = blockIdx.x;  // 0..390
  int tid = threadIdx.x;
  h[tid] = 0;
  __syncthreads();
  int i0 = b * NBLK_E;
  int start = counts[i0] + part[i0 >> 10];
  int end = N_EDGES;
  if (b != NBK - 1) {
    int i1 = (b + 1) * NBLK_E;
    end = counts[i1] + part[i1 >> 10];
  }
  for (int e = start + tid; e < end; e += 256) {
    uint32 p = __builtin_nontemporal_load(&psort[e]);
    int dl = (int)(p >> 24);
    int s = (int)(p & 0xFFFFFFu);
    int r = atomicAdd(&h[dl], 1);
    csrp[(size_t)(b * 256 + dl) * CAP + r] = s;
  }
  __syncthreads();
  int node = b * 256 + tid;
  if (node < N_NODES) degi[node] = h[tid];
}

// ---- mean aggregation: 16 lanes/node, uint2/lane, 16-deep MLP ---------------
__global__ __launch_bounds__(256) void k_agg(const unsigned char* __restrict__ in8,
                                             unsigned short* __restrict__ out,
                                             const int* __restrict__ degi,
                                             const int* __restrict__ csrp) {
  int grp = threadIdx.x >> 4;   // 16 groups/block, one node each
  int l16 = threadIdx.x & 15;   // elem chunk [l16*8, l16*8+8)
  int node = blockIdx.x * 16 + grp;
  size_t start = (size_t)node * CAP;
  int cnt = degi[node];
  const unsigned char* base = in8 + l16 * 8;
  f32x2 a0 = {0.f, 0.f}, a1 = {0.f, 0.f}, a2 = {0.f, 0.f}, a3 = {0.f, 0.f};
#define ACC(v)                                                   \
    a0 += __builtin_amdgcn_cvt_pk_f32_fp8((int)v.x, false);      \
    a1 += __builtin_amdgcn_cvt_pk_f32_fp8((int)v.x, true);       \
    a2 += __builtin_amdgcn_cvt_pk_f32_fp8((int)v.y, false);      \
    a3 += __builtin_amdgcn_cvt_pk_f32_fp8((int)v.y, true);
  int i = 0;
  for (; i + 16 <= cnt; i += 16) {
    int4 x0 = *(const int4*)(csrp + start + i);
    int4 x1 = *(const int4*)(csrp + start + i + 4);
    int4 x2 = *(const int4*)(csrp + start + i + 8);
    int4 x3 = *(const int4*)(csrp + start + i + 12);
    uint2 v0 = *(const uint2*)(base + (size_t)x0.x * EMB);
    uint2 v1 = *(const uint2*)(base + (size_t)x0.y * EMB);
    uint2 v2 = *(const uint2*)(base + (size_t)x0.z * EMB);
    uint2 v3 = *(const uint2*)(base + (size_t)x0.w * EMB);
    uint2 v4 = *(const uint2*)(base + (size_t)x1.x * EMB);
    uint2 v5 = *(const uint2*)(base + (size_t)x1.y * EMB);
    uint2 v6 = *(const uint2*)(base + (size_t)x1.z * EMB);
    uint2 v7 = *(const uint2*)(base + (size_t)x1.w * EMB);
    uint2 v8 = *(const uint2*)(base + (size_t)x2.x * EMB);
    uint2 v9 = *(const uint2*)(base + (size_t)x2.y * EMB);
    uint2 va = *(const uint2*)(base + (size_t)x2.z * EMB);
    uint2 vb = *(const uint2*)(base + (size_t)x2.w * EMB);
    uint2 vc = *(const uint2*)(base + (size_t)x3.x * EMB);
    uint2 vd = *(const uint2*)(base + (size_t)x3.y * EMB);
    uint2 ve = *(const uint2*)(base + (size_t)x3.z * EMB);
    uint2 vf = *(const uint2*)(base + (size_t)x3.w * EMB);
    ACC(v0) ACC(v1) ACC(v2) ACC(v3) ACC(v4) ACC(v5) ACC(v6) ACC(v7)
    ACC(v8) ACC(v9) ACC(va) ACC(vb) ACC(vc) ACC(vd) ACC(ve) ACC(vf)
  }
  for (; i + 8 <= cnt; i += 8) {
    int s0 = csrp[start + i + 0];
    int s1 = csrp[start + i + 1];
    int s2 = csrp[start + i + 2];
    int s3 = csrp[start + i + 3];
    int s4 = csrp[start + i + 4];
    int s5 = csrp[start + i + 5];
    int s6 = csrp[start + i + 6];
    int s7 = csrp[start + i + 7];
    uint2 v0 = *(const uint2*)(base + (size_t)s0 * EMB);
    uint2 v1 = *(const uint2*)(base + (size_t)s1 * EMB);
    uint2 v2 = *(const uint2*)(base + (size_t)s2 * EMB);
    uint2 v3 = *(const uint2*)(base + (size_t)s3 * EMB);
    uint2 v4 = *(const uint2*)(base + (size_t)s4 * EMB);
    uint2 v5 = *(const uint2*)(base + (size_t)s5 * EMB);
    uint2 v6 = *(const uint2*)(base + (size_t)s6 * EMB);
    uint2 v7 = *(const uint2*)(base + (size_t)s7 * EMB);
    ACC(v0) ACC(v1) ACC(v2) ACC(v3) ACC(v4) ACC(v5) ACC(v6) ACC(v7)
  }
  for (; i < cnt; ++i) {
    int s = csrp[start + i];
    uint2 v = *(const uint2*)(base + (size_t)s * EMB);
    ACC(v)
  }
#undef ACC
  float di = cnt > 0 ? 1.0f / (float)cnt : 0.0f;
  uint4 o;
  o.x = (uint32)f2bf(a0.x * di) | ((uint32)f2bf(a0.y * di) << 16);
  o.y = (uint32)f2bf(a1.x * di) | ((uint32)f2bf(a1.y * di) << 16);
  o.z = (uint32)f2bf(a2.x * di) | ((uint32)f2bf(a2.y * di) << 16);
  o.w = (uint32)f2bf(a3.x * di) | ((uint32)f2bf(a3.y * di) << 16);
  *(uint4*)(out + (size_t)node * EMB + l16 * 8) = o;
}

// ---- fused MFMA GEMM, Wcat LDS-staged (swizzled): 8 waves x 16 rows ---------
__global__ __launch_bounds__(512) void k_gemm(const unsigned short* __restrict__ A,
                                              const unsigned short* __restrict__ S,
                                              const unsigned short* __restrict__ Wcat,
                                              const float* __restrict__ bias,
                                              unsigned short* __restrict__ out,
                                              unsigned char* __restrict__ out8) {
  __shared__ unsigned char ldsW[65536];  // 128 cols x 256 k x bf16, XOR-swizzled
  int tid = threadIdx.x;
  {
    const uint4* w4 = (const uint4*)Wcat;
#pragma unroll
    for (int it = 0; it < 8; ++it) {
      int i = tid + it * 512;  // 4096 x 16B
      uint4 v = w4[i];
      unsigned a = (unsigned)i << 4;
      a ^= ((a >> 9) & 7u) << 4;
      *(uint4*)(ldsW + a) = v;
    }
  }
  __syncthreads();

  int wid = tid >> 6;
  int lane = tid & 63;
  int rows0 = blockIdx.x * 128 + wid * 16;
  int r = lane & 15;
  int khalf = lane >> 4;
  int arow = rows0 + r;
  if (arow > N_NODES - 1) arow = N_NODES - 1;
  const unsigned short* Abase = A + (size_t)arow * EMB + khalf * 8;
  const unsigned short* Sbase = S + (size_t)arow * EMB + khalf * 8;
  unsigned bswz = ((unsigned)(r & 7)) << 4;

  f32x4 acc[8] = {};
#pragma unroll
  for (int kc = 0; kc < 8; ++kc) {
    const unsigned short* p = (kc < 4) ? (Abase + kc * 32) : (Sbase + (kc - 4) * 32);
    bf16x8 a = *(const bf16x8*)p;
#pragma unroll
    for (int jc = 0; jc < 8; ++jc) {
      unsigned addr = (((unsigned)(jc * 16 + r)) << 9) + ((unsigned)kc << 6) +
                      ((unsigned)khalf << 4);
      bf16x8 b = *(const bf16x8*)(ldsW + (addr ^ bswz));
      acc[jc] = __builtin_amdgcn_mfma_f32_16x16x32_bf16(a, b, acc[jc], 0, 0, 0);
    }
  }

  int rbase = (lane >> 4) * 4;
#pragma unroll
  for (int jc = 0; jc < 8; ++jc) {
    int col = jc * 16 + r;
    float bv = bias[col];
#pragma unroll
    for (int q = 0; q < 4; ++q) {
      int row = rows0 + rbase + q;
      if (row < N_NODES) {
        float v = fmaxf(acc[jc][q] + bv, 0.f);
        out[(size_t)row * EMB + col] = f2bf(v);
        if (out8) out8[(size_t)row * EMB + col] = f2fp8(v);
      }
    }
  }
}

// ---------------- mean pooling per graph + linear head -----------------------
__global__ void k_pool(const unsigned short* __restrict__ h, const int* __restrict__ batch,
                       const float* __restrict__ lw, const float* __restrict__ lb,
                       float* __restrict__ out) {
  int g = blockIdx.x;
  int tid = threadIdx.x;  // 128
  int lo = 0, hi = N_NODES;
  while (lo < hi) {
    int mid = (lo + hi) >> 1;
    if (batch[mid] < g) lo = mid + 1; else hi = mid;
  }
  int lo2 = lo, hi2 = N_NODES;
  while (lo2 < hi2) {
    int mid = (lo2 + hi2) >> 1;
    if (batch[mid] < g + 1) lo2 = mid + 1; else hi2 = mid;
  }
  float sum = 0.f;
  for (int n = lo; n < lo2; ++n) sum += bf2f(h[(size_t)n * EMB + tid]);
  int cnt = lo2 - lo;
  float pooled = sum / fmaxf((float)cnt, 1.0f);
  __shared__ float pl[EMB];
  pl[tid] = pooled;
  __syncthreads();
  if (tid < N_CLASS) {
    float o = lb[tid];
    for (int d = 0; d < EMB; ++d) o += pl[d] * lw[tid * EMB + d];
    out[g * N_CLASS + tid] = o;
  }
}

extern "C" void kernel_launch(void* const* d_in, const int* in_sizes, int n_in,
                              void* d_out, int out_size, void* d_ws, size_t ws_size,
                              hipStream_t stream) {
  const int* nf = (const int*)d_in[0];
  const int* ei = (const int*)d_in[1];
  const int* batch = (const int*)d_in[2];
  const float* se = (const float*)d_in[3];
  const float* ce = (const float*)d_in[4];
  const float* pe = (const float*)d_in[5];
  const float* w1l = (const float*)d_in[6];
  const float* b1l = (const float*)d_in[7];
  const float* w1r = (const float*)d_in[8];
  const float* w2l = (const float*)d_in[9];
  const float* b2l = (const float*)d_in[10];
  const float* w2r = (const float*)d_in[11];
  const float* linw = (const float*)d_in[12];
  const float* linb = (const float*)d_in[13];
  float* out = (float*)d_out;

  char* ws = (char*)d_ws;
  size_t off = 0;
  auto alloc = [&](size_t bytes) {
    void* p = ws + off;
    off = (off + bytes + 255) & ~(size_t)255;
    return p;
  };
  unsigned short* X = (unsigned short*)alloc((size_t)N_NODES * EMB * 2);
  unsigned short* H = (unsigned short*)alloc((size_t)N_NODES * EMB * 2);
  unsigned short* X2 = (unsigned short*)alloc((size_t)N_NODES * EMB * 2);
  unsigned short* AGG = (unsigned short*)alloc((size_t)N_NODES * EMB * 2);
  unsigned char* X8 = (unsigned char*)alloc((size_t)N_NODES * EMB);
  unsigned char* H8 = (unsigned char*)alloc((size_t)N_NODES * EMB);
  unsigned short* WC1 = (unsigned short*)alloc((size_t)256 * EMB * 2);
  unsigned short* WC2 = (unsigned short*)alloc((size_t)256 * EMB * 2);
  int* degi = (int*)alloc((size_t)N_NODES * 4);
  int* counts = (int*)alloc((size_t)NTOT * 4);
  int* part = (int*)alloc((size_t)512 * 4);
  uint32* psort = (uint32*)alloc((size_t)N_EDGES * 4);
  int* csrp = (int*)alloc((size_t)N_NODES * CAP * 4);

  const int* srcv = ei;
  const int* dstv = ei + N_EDGES;

  k_hist<<<NBLK_E + EMBED_BLKS + WCAT_BLKS, 256, 0, stream>>>(
      dstv, counts, nf, se, ce, pe, X, X8, w1l, w1r, w2l, w2r, WC1, WC2);
  k_scan1<<<NB_SCAN, SCAN_B, 0, stream>>>(counts, part);
  k_scan2<<<1, 512, 0, stream>>>(part);
  k_part<<<NBLK_E, 1024, 0, stream>>>(srcv, dstv, counts, part, psort);
  k_csr<<<NBK, 256, 0, stream>>>(psort, counts, part, csrp, degi);

  k_agg<<<N_NODES / 16, 256, 0, stream>>>(X8, AGG, degi, csrp);
  k_gemm<<<(N_NODES + 127) / 128, 512, 0, stream>>>(AGG, X, WC1, b1l, H, H8);
  k_agg<<<N_NODES / 16, 256, 0, stream>>>(H8, AGG, degi, csrp);
  k_gemm<<<(N_NODES + 127) / 128, 512, 0, stream>>>(AGG, H, WC2, b2l, X2, nullptr);
  k_pool<<<N_GRAPH, EMB, 0, stream>>>(X2, batch, linw, linb, out);
}

// Round 23
// 270.320 us; speedup vs baseline: 1.0400x; 1.0400x over previous
//
#include <hip/hip_runtime.h>

#define N_NODES 100000
#define N_EDGES 3200000
#define EMB 128
#define N_GRAPH 1024
#define N_CLASS 10
#define CAP 96  // padded CSR capacity; P(deg>=96)~4e-20 per node (mean deg 32)

#define EPB 5120                         // edges per hist/scatter block
#define NBLK_E (N_EDGES / EPB)           // 625
#define NBK 391                          // ceil(100000/256) buckets of 256 nodes
#define NTOT (NBK * NBLK_E)              // 244375
#define SCAN_B 1024
#define NB_SCAN ((NTOT + SCAN_B - 1) / SCAN_B)  // 239

#define EMBED_BLKS (N_NODES * 16 / 256)  // 6250
#define WCAT_BLKS 256                    // 2 x 128

typedef unsigned int uint32;
typedef __attribute__((ext_vector_type(8))) short bf16x8;
typedef __attribute__((ext_vector_type(4))) float f32x4;
typedef __attribute__((ext_vector_type(2))) float f32x2;

__device__ inline unsigned short f2bf(float f) {
  unsigned u = __float_as_uint(f);
  u += 0x7fffu + ((u >> 16) & 1u);
  return (unsigned short)(u >> 16);
}
__device__ inline float bf2f(unsigned short s) {
  return __uint_as_float(((unsigned)s) << 16);
}
__device__ inline unsigned char f2fp8(float v) {
  return (unsigned char)(__builtin_amdgcn_cvt_pk_fp8_f32(v, v, 0, false) & 0xff);
}

// ---- A: fused bucket-histogram (LDS atomics only) + embedding + wcat --------
__global__ __launch_bounds__(256) void k_hist(
    const int* __restrict__ dst, int* __restrict__ counts,
    const int* __restrict__ nf, const float* __restrict__ se,
    const float* __restrict__ ce, const float* __restrict__ pe,
    unsigned short* __restrict__ X, unsigned char* __restrict__ X8,
    const float* __restrict__ w1l, const float* __restrict__ w1r,
    const float* __restrict__ w2l, const float* __restrict__ w2r,
    unsigned short* __restrict__ wc1, unsigned short* __restrict__ wc2) {
  int b = blockIdx.x;
  int tid = threadIdx.x;
  if (b < NBLK_E) {
    __shared__ int h[NBK];
    for (int i = tid; i < NBK; i += 256) h[i] = 0;
    __syncthreads();
    int base = b * EPB;
#pragma unroll
    for (int it = 0; it < 20; ++it) {
      int d = dst[base + it * 256 + tid];
      atomicAdd(&h[d >> 8], 1);
    }
    __syncthreads();
    for (int i = tid; i < NBK; i += 256) counts[i * NBLK_E + b] = h[i];
  } else if (b < NBLK_E + EMBED_BLKS) {
    int gid = (b - NBLK_E) * 256 + tid;  // N_NODES*16 threads
    int node = gid >> 4;
    int q = (gid & 15) * 8;
    int s = nf[node * 3 + 0];
    int c = nf[node * 3 + 1];
    int p = nf[node * 3 + 2];
    const float* ps = se + s * EMB + q;
    const float* pc = ce + c * EMB + q;
    const float* pp = pe + p * EMB + q;
    float4 a0 = *(const float4*)ps, a1 = *(const float4*)(ps + 4);
    float4 b0 = *(const float4*)pc, b1 = *(const float4*)(pc + 4);
    float4 d0 = *(const float4*)pp, d1 = *(const float4*)(pp + 4);
    float r0 = a0.x + b0.x + d0.x, r1 = a0.y + b0.y + d0.y;
    float r2 = a0.z + b0.z + d0.z, r3 = a0.w + b0.w + d0.w;
    float r4 = a1.x + b1.x + d1.x, r5 = a1.y + b1.y + d1.y;
    float r6 = a1.z + b1.z + d1.z, r7 = a1.w + b1.w + d1.w;
    uint4 o;
    o.x = (uint32)f2bf(r0) | ((uint32)f2bf(r1) << 16);
    o.y = (uint32)f2bf(r2) | ((uint32)f2bf(r3) << 16);
    o.z = (uint32)f2bf(r4) | ((uint32)f2bf(r5) << 16);
    o.w = (uint32)f2bf(r6) | ((uint32)f2bf(r7) << 16);
    *(uint4*)(X + (size_t)node * EMB + q) = o;
    int w0 = __builtin_amdgcn_cvt_pk_fp8_f32(r0, r1, 0, false);
    w0 = __builtin_amdgcn_cvt_pk_fp8_f32(r2, r3, w0, true);
    int w1 = __builtin_amdgcn_cvt_pk_fp8_f32(r4, r5, 0, false);
    w1 = __builtin_amdgcn_cvt_pk_fp8_f32(r6, r7, w1, true);
    uint2 o8;
    o8.x = (uint32)w0;
    o8.y = (uint32)w1;
    *(uint2*)(X8 + (size_t)node * EMB + q) = o8;
  } else {
    int wb = b - (NBLK_E + EMBED_BLKS);  // 0..255
    const float* wl = (wb < 128) ? w1l : w2l;
    const float* wr = (wb < 128) ? w1r : w2r;
    unsigned short* wcat = (wb < 128) ? wc1 : wc2;
    int gid = (wb & 127) * 256 + tid;  // 32768 elems
    int j = gid >> 8;
    int k = gid & 255;
    float v = (k < EMB) ? wl[j * EMB + k] : wr[j * EMB + (k - EMB)];
    wcat[gid] = f2bf(v);
  }
}

// ---------------- scan over flattened counts [bucket][block] -----------------
__global__ void k_scan1(int* __restrict__ data, int* __restrict__ part) {
  __shared__ int t[SCAN_B];
  int tid = threadIdx.x;
  int gid = blockIdx.x * SCAN_B + tid;
  int v = (gid < NTOT) ? data[gid] : 0;
  t[tid] = v;
  __syncthreads();
  for (int s = 1; s < SCAN_B; s <<= 1) {
    int u = (tid >= s) ? t[tid - s] : 0;
    __syncthreads();
    t[tid] += u;
    __syncthreads();
  }
  if (gid < NTOT) data[gid] = t[tid] - v;  // exclusive, block-local
  if (tid == SCAN_B - 1) part[blockIdx.x] = t[tid];
}

__global__ void k_scan2(int* __restrict__ part) {
  __shared__ int t[512];
  int tid = threadIdx.x;  // 512
  int v = (tid < NB_SCAN) ? part[tid] : 0;
  t[tid] = v;
  __syncthreads();
  for (int s = 1; s < 512; s <<= 1) {
    int u = (tid >= s) ? t[tid - s] : 0;
    __syncthreads();
    t[tid] += u;
    __syncthreads();
  }
  if (tid < NB_SCAN) part[tid] = t[tid] - v;
}

// ---- C: partition packed (dlocal,src); scanned column preloaded in LDS ------
// 1024 threads/block for occupancy (5 edges/thread)
__global__ __launch_bounds__(1024) void k_part(const int* __restrict__ src,
                                               const int* __restrict__ dst,
                                               const int* __restrict__ counts,
                                               const int* __restrict__ part,
                                               uint32* __restrict__ psort) {
  __shared__ int h[NBK];
  __shared__ int scol[NBK];
  int b = blockIdx.x;
  int tid = threadIdx.x;
  for (int i = tid; i < NBK; i += 1024) {
    h[i] = 0;
    int idx = i * NBLK_E + b;
    scol[i] = counts[idx] + part[idx >> 10];
  }
  __syncthreads();
  int base = b * EPB;
#pragma unroll
  for (int it = 0; it < 5; ++it) {
    int e = base + it * 1024 + tid;
    int d = dst[e];
    int s = src[e];
    int r = atomicAdd(&h[d >> 8], 1);
    psort[scol[d >> 8] + r] = ((uint32)(d & 255) << 24) | (uint32)s;
  }
}

// ---- D: per-bucket CSR build (LDS ranks, L2-local scatter) + degi -----------
__global__ __launch_bounds__(256) void k_csr(const uint32* __restrict__ psort,
                                             const int* __restrict__ counts,
                                             const int* __restrict__ part,
                                             int* __restrict__ csrp,
                                             int* __restrict__ degi) {
  __shared__ int h[256];
  int b = blockIdx.x;  // 0..390
  int tid = threadIdx.x;
  h[tid] = 0;
  __syncthreads();
  int i0 = b * NBLK_E;
  int start = counts[i0] + part[i0 >> 10];
  int end = N_EDGES;
  if (b != NBK - 1) {
    int i1 = (b + 1) * NBLK_E;
    end = counts[i1] + part[i1 >> 10];
  }
  for (int e = start + tid; e < end; e += 256) {
    uint32 p = psort[e];
    int dl = (int)(p >> 24);
    int s = (int)(p & 0xFFFFFFu);
    int r = atomicAdd(&h[dl], 1);
    csrp[(size_t)(b * 256 + dl) * CAP + r] = s;
  }
  __syncthreads();
  int node = b * 256 + tid;
  if (node < N_NODES) degi[node] = h[tid];
}

// ---- mean aggregation: 16 lanes/node, uint2 (8 fp8) per lane ----------------
__global__ __launch_bounds__(256) void k_agg(const unsigned char* __restrict__ in8,
                                             unsigned short* __restrict__ out,
                                             const int* __restrict__ degi,
                                             const int* __restrict__ csrp) {
  int grp = threadIdx.x >> 4;   // 16 groups/block, one node each
  int l16 = threadIdx.x & 15;   // elem chunk [l16*8, l16*8+8)
  int node = blockIdx.x * 16 + grp;
  size_t start = (size_t)node * CAP;
  int cnt = degi[node];
  const unsigned char* base = in8 + l16 * 8;
  f32x2 a0 = {0.f, 0.f}, a1 = {0.f, 0.f}, a2 = {0.f, 0.f}, a3 = {0.f, 0.f};
  int i = 0;
  for (; i + 8 <= cnt; i += 8) {
    int s0 = csrp[start + i + 0];
    int s1 = csrp[start + i + 1];
    int s2 = csrp[start + i + 2];
    int s3 = csrp[start + i + 3];
    int s4 = csrp[start + i + 4];
    int s5 = csrp[start + i + 5];
    int s6 = csrp[start + i + 6];
    int s7 = csrp[start + i + 7];
    uint2 v0 = *(const uint2*)(base + (size_t)s0 * EMB);
    uint2 v1 = *(const uint2*)(base + (size_t)s1 * EMB);
    uint2 v2 = *(const uint2*)(base + (size_t)s2 * EMB);
    uint2 v3 = *(const uint2*)(base + (size_t)s3 * EMB);
    uint2 v4 = *(const uint2*)(base + (size_t)s4 * EMB);
    uint2 v5 = *(const uint2*)(base + (size_t)s5 * EMB);
    uint2 v6 = *(const uint2*)(base + (size_t)s6 * EMB);
    uint2 v7 = *(const uint2*)(base + (size_t)s7 * EMB);
#define ACC(v)                                                   \
    a0 += __builtin_amdgcn_cvt_pk_f32_fp8((int)v.x, false);      \
    a1 += __builtin_amdgcn_cvt_pk_f32_fp8((int)v.x, true);       \
    a2 += __builtin_amdgcn_cvt_pk_f32_fp8((int)v.y, false);      \
    a3 += __builtin_amdgcn_cvt_pk_f32_fp8((int)v.y, true);
    ACC(v0) ACC(v1) ACC(v2) ACC(v3) ACC(v4) ACC(v5) ACC(v6) ACC(v7)
  }
  for (; i < cnt; ++i) {
    int s = csrp[start + i];
    uint2 v = *(const uint2*)(base + (size_t)s * EMB);
    ACC(v)
  }
#undef ACC
  float di = cnt > 0 ? 1.0f / (float)cnt : 0.0f;
  uint4 o;
  o.x = (uint32)f2bf(a0.x * di) | ((uint32)f2bf(a0.y * di) << 16);
  o.y = (uint32)f2bf(a1.x * di) | ((uint32)f2bf(a1.y * di) << 16);
  o.z = (uint32)f2bf(a2.x * di) | ((uint32)f2bf(a2.y * di) << 16);
  o.w = (uint32)f2bf(a3.x * di) | ((uint32)f2bf(a3.y * di) << 16);
  *(uint4*)(out + (size_t)node * EMB + l16 * 8) = o;
}

// ---- fused MFMA GEMM, Wcat LDS-staged (swizzled): 8 waves x 16 rows ---------
__global__ __launch_bounds__(512) void k_gemm(const unsigned short* __restrict__ A,
                                              const unsigned short* __restrict__ S,
                                              const unsigned short* __restrict__ Wcat,
                                              const float* __restrict__ bias,
                                              unsigned short* __restrict__ out,
                                              unsigned char* __restrict__ out8) {
  __shared__ unsigned char ldsW[65536];  // 128 cols x 256 k x bf16, XOR-swizzled
  int tid = threadIdx.x;
  {
    const uint4* w4 = (const uint4*)Wcat;
#pragma unroll
    for (int it = 0; it < 8; ++it) {
      int i = tid + it * 512;  // 4096 x 16B
      uint4 v = w4[i];
      unsigned a = (unsigned)i << 4;
      a ^= ((a >> 9) & 7u) << 4;
      *(uint4*)(ldsW + a) = v;
    }
  }
  __syncthreads();

  int wid = tid >> 6;
  int lane = tid & 63;
  int rows0 = blockIdx.x * 128 + wid * 16;
  int r = lane & 15;
  int khalf = lane >> 4;
  int arow = rows0 + r;
  if (arow > N_NODES - 1) arow = N_NODES - 1;
  const unsigned short* Abase = A + (size_t)arow * EMB + khalf * 8;
  const unsigned short* Sbase = S + (size_t)arow * EMB + khalf * 8;
  unsigned bswz = ((unsigned)(r & 7)) << 4;

  f32x4 acc[8] = {};
#pragma unroll
  for (int kc = 0; kc < 8; ++kc) {
    const unsigned short* p = (kc < 4) ? (Abase + kc * 32) : (Sbase + (kc - 4) * 32);
    bf16x8 a = *(const bf16x8*)p;
#pragma unroll
    for (int jc = 0; jc < 8; ++jc) {
      unsigned addr = (((unsigned)(jc * 16 + r)) << 9) + ((unsigned)kc << 6) +
                      ((unsigned)khalf << 4);
      bf16x8 b = *(const bf16x8*)(ldsW + (addr ^ bswz));
      acc[jc] = __builtin_amdgcn_mfma_f32_16x16x32_bf16(a, b, acc[jc], 0, 0, 0);
    }
  }

  int rbase = (lane >> 4) * 4;
#pragma unroll
  for (int jc = 0; jc < 8; ++jc) {
    int col = jc * 16 + r;
    float bv = bias[col];
#pragma unroll
    for (int q = 0; q < 4; ++q) {
      int row = rows0 + rbase + q;
      if (row < N_NODES) {
        float v = fmaxf(acc[jc][q] + bv, 0.f);
        out[(size_t)row * EMB + col] = f2bf(v);
        if (out8) out8[(size_t)row * EMB + col] = f2fp8(v);
      }
    }
  }
}

// ---------------- mean pooling per graph + linear head -----------------------
__global__ void k_pool(const unsigned short* __restrict__ h, const int* __restrict__ batch,
                       const float* __restrict__ lw, const float* __restrict__ lb,
                       float* __restrict__ out) {
  int g = blockIdx.x;
  int tid = threadIdx.x;  // 128
  int lo = 0, hi = N_NODES;
  while (lo < hi) {
    int mid = (lo + hi) >> 1;
    if (batch[mid] < g) lo = mid + 1; else hi = mid;
  }
  int lo2 = lo, hi2 = N_NODES;
  while (lo2 < hi2) {
    int mid = (lo2 + hi2) >> 1;
    if (batch[mid] < g + 1) lo2 = mid + 1; else hi2 = mid;
  }
  float sum = 0.f;
  for (int n = lo; n < lo2; ++n) sum += bf2f(h[(size_t)n * EMB + tid]);
  int cnt = lo2 - lo;
  float pooled = sum / fmaxf((float)cnt, 1.0f);
  __shared__ float pl[EMB];
  pl[tid] = pooled;
  __syncthreads();
  if (tid < N_CLASS) {
    float o = lb[tid];
    for (int d = 0; d < EMB; ++d) o += pl[d] * lw[tid * EMB + d];
    out[g * N_CLASS + tid] = o;
  }
}

extern "C" void kernel_launch(void* const* d_in, const int* in_sizes, int n_in,
                              void* d_out, int out_size, void* d_ws, size_t ws_size,
                              hipStream_t stream) {
  const int* nf = (const int*)d_in[0];
  const int* ei = (const int*)d_in[1];
  const int* batch = (const int*)d_in[2];
  const float* se = (const float*)d_in[3];
  const float* ce = (const float*)d_in[4];
  const float* pe = (const float*)d_in[5];
  const float* w1l = (const float*)d_in[6];
  const float* b1l = (const float*)d_in[7];
  const float* w1r = (const float*)d_in[8];
  const float* w2l = (const float*)d_in[9];
  const float* b2l = (const float*)d_in[10];
  const float* w2r = (const float*)d_in[11];
  const float* linw = (const float*)d_in[12];
  const float* linb = (const float*)d_in[13];
  float* out = (float*)d_out;

  char* ws = (char*)d_ws;
  size_t off = 0;
  auto alloc = [&](size_t bytes) {
    void* p = ws + off;
    off = (off + bytes + 255) & ~(size_t)255;
    return p;
  };
  unsigned short* X = (unsigned short*)alloc((size_t)N_NODES * EMB * 2);
  unsigned short* H = (unsigned short*)alloc((size_t)N_NODES * EMB * 2);
  unsigned short* X2 = (unsigned short*)alloc((size_t)N_NODES * EMB * 2);
  unsigned short* AGG = (unsigned short*)alloc((size_t)N_NODES * EMB * 2);
  unsigned char* X8 = (unsigned char*)alloc((size_t)N_NODES * EMB);
  unsigned char* H8 = (unsigned char*)alloc((size_t)N_NODES * EMB);
  unsigned short* WC1 = (unsigned short*)alloc((size_t)256 * EMB * 2);
  unsigned short* WC2 = (unsigned short*)alloc((size_t)256 * EMB * 2);
  int* degi = (int*)alloc((size_t)N_NODES * 4);
  int* counts = (int*)alloc((size_t)NTOT * 4);
  int* part = (int*)alloc((size_t)512 * 4);
  uint32* psort = (uint32*)alloc((size_t)N_EDGES * 4);
  int* csrp = (int*)alloc((size_t)N_NODES * CAP * 4);

  const int* srcv = ei;
  const int* dstv = ei + N_EDGES;

  k_hist<<<NBLK_E + EMBED_BLKS + WCAT_BLKS, 256, 0, stream>>>(
      dstv, counts, nf, se, ce, pe, X, X8, w1l, w1r, w2l, w2r, WC1, WC2);
  k_scan1<<<NB_SCAN, SCAN_B, 0, stream>>>(counts, part);
  k_scan2<<<1, 512, 0, stream>>>(part);
  k_part<<<NBLK_E, 1024, 0, stream>>>(srcv, dstv, counts, part, psort);
  k_csr<<<NBK, 256, 0, stream>>>(psort, counts, part, csrp, degi);

  k_agg<<<N_NODES / 16, 256, 0, stream>>>(X8, AGG, degi, csrp);
  k_gemm<<<(N_NODES + 127) / 128, 512, 0, stream>>>(AGG, X, WC1, b1l, H, H8);
  k_agg<<<N_NODES / 16, 256, 0, stream>>>(H8, AGG, degi, csrp);
  k_gemm<<<(N_NODES + 127) / 128, 512, 0, stream>>>(AGG, H, WC2, b2l, X2, nullptr);
  k_pool<<<N_GRAPH, EMB, 0, stream>>>(X2, batch, linw, linb, out);
}